// Round 6
// baseline (321.059 us; speedup 1.0000x reference)
//
#include <hip/hip_runtime.h>
#include <cstdint>
#include <cstddef>

typedef _Float16 half_t;
typedef _Float16 half8 __attribute__((ext_vector_type(8)));
typedef float floatx4 __attribute__((ext_vector_type(4)));

#define E_ 8
#define D_ 512
#define H_ 2048
#define NTOK 1024
#define NP 2048            // NTOK * top_k
#define CAP 1024           // per-expert row capacity (worst case: every token picks this expert)

__device__ __forceinline__ float gelu_f(float x) {
    return 0.5f * x * (1.0f + erff(x * 0.7071067811865476f));
}

__device__ __forceinline__ half8 cvt8(const floatx4& f0, const floatx4& f1) {
    half8 h = { (half_t)f0[0], (half_t)f0[1], (half_t)f0[2], (half_t)f0[3],
                (half_t)f1[0], (half_t)f1[1], (half_t)f1[2], (half_t)f1[3] };
    return h;
}

// ---------------- gate + scatter: logits, top2, softmax, rank, f16 row to both expert slabs ----------------
__global__ __launch_bounds__(256) void gate_scatter_kernel(
        const float* __restrict__ inp, const float* __restrict__ gate_w,
        const float* __restrict__ gate_b,
        float* __restrict__ score, int* __restrict__ idx,
        int* __restrict__ pos_of_pair, int* __restrict__ cnt_g,
        half_t* __restrict__ Xg) {
    int n = blockIdx.x * 4 + (threadIdx.x >> 6);
    int lane = threadIdx.x & 63;
    const floatx4* xr = (const floatx4*)(inp + (size_t)n * D_);
    floatx4 x0 = xr[lane * 2], x1 = xr[lane * 2 + 1];
    float l[E_];
    #pragma unroll
    for (int e = 0; e < E_; e++) {
        const floatx4* gr = (const floatx4*)(gate_w + (size_t)e * D_);
        floatx4 g0 = gr[lane * 2], g1 = gr[lane * 2 + 1];
        float p = x0[0]*g0[0] + x0[1]*g0[1] + x0[2]*g0[2] + x0[3]*g0[3]
                + x1[0]*g1[0] + x1[1]*g1[1] + x1[2]*g1[2] + x1[3]*g1[3];
        #pragma unroll
        for (int m = 1; m < 64; m <<= 1) p += __shfl_xor(p, m);
        l[e] = p + gate_b[e];
    }
    int e0 = 0; float v0 = l[0];
    #pragma unroll
    for (int e = 1; e < E_; e++) if (l[e] > v0) { v0 = l[e]; e0 = e; }
    int e1 = -1; float v1 = -3.4e38f;
    #pragma unroll
    for (int e = 0; e < E_; e++) if (e != e0 && l[e] > v1) { v1 = l[e]; e1 = e; }
    int p0 = 0, p1 = 0;
    if (lane == 0) {
        float s1 = expf(v1 - v0);
        float den = 1.0f + s1;
        score[2 * n]     = 1.0f / den;
        score[2 * n + 1] = s1 / den;
        idx[2 * n]     = e0;
        idx[2 * n + 1] = e1;
        p0 = e0 * CAP + atomicAdd(&cnt_g[e0], 1);
        p1 = e1 * CAP + atomicAdd(&cnt_g[e1], 1);
        pos_of_pair[2 * n]     = p0;
        pos_of_pair[2 * n + 1] = p1;
    }
    p0 = __shfl(p0, 0);
    p1 = __shfl(p1, 0);
    half8 h = { (half_t)x0[0], (half_t)x0[1], (half_t)x0[2], (half_t)x0[3],
                (half_t)x1[0], (half_t)x1[1], (half_t)x1[2], (half_t)x1[3] };
    *(half8*)(Xg + (size_t)p0 * D_ + lane * 8) = h;
    *(half8*)(Xg + (size_t)p1 * D_ + lane * 8) = h;
}

// ======== wave-autonomous GEMM: each wave owns a 32x64 tile, no LDS, no barriers ========
// A: f16 rows (Xg / Y1 slabs); B: fp32 weights converted in-register to f16.
// Register prefetch: load k-step i+1 while doing the 8 MFMAs of step i.

// ---------------- GEMM1: Y1[slab] = gelu(Xg @ W1[e]^T + b1[e]) ----------------
// jobs: 256 m-slots (8 experts x 32 slots of 32 rows) x 32 n-tiles (64 cols) = 8192 waves
__global__ __launch_bounds__(256, 3) void gemm1_kernel(
        const half_t* __restrict__ Xg, const float* __restrict__ w1,
        const float* __restrict__ b1, const int* __restrict__ cnt_g,
        half_t* __restrict__ Y1) {
    int wave = threadIdx.x >> 6, lane = threadIdx.x & 63;
    int quad = lane >> 4, l16 = lane & 15;
    int job = blockIdx.x * 4 + wave;
    int mslot = job >> 5;               // 0..255 ; uniform within a block
    int ncol  = (job & 31) * 64;
    int e = mslot >> 5, ti = mslot & 31;
    int valid = cnt_g[e] - ti * 32;
    if (valid <= 0) return;             // block-uniform exit
    int cnt = valid < 32 ? valid : 32;
    int row0 = e * CAP + ti * 32;

    const half_t* Ap = Xg + (size_t)(row0 + l16) * D_ + quad * 8;
    const float* Bp[4];
    #pragma unroll
    for (int ni = 0; ni < 4; ni++)
        Bp[ni] = w1 + ((size_t)e * H_ + ncol + ni * 16 + l16) * D_ + quad * 8;

    half8 a0 = *(const half8*)(Ap);
    half8 a1 = *(const half8*)(Ap + 16 * D_);
    floatx4 bb[4][2];
    #pragma unroll
    for (int ni = 0; ni < 4; ni++) {
        bb[ni][0] = *(const floatx4*)(Bp[ni]);
        bb[ni][1] = *(const floatx4*)(Bp[ni] + 4);
    }
    floatx4 acc[2][4] = {};
    for (int ks = 0; ks < 16; ks++) {
        int kn = (ks + 1) * 32;
        half8 na0, na1;
        floatx4 nb[4][2];
        if (ks < 15) {
            na0 = *(const half8*)(Ap + kn);
            na1 = *(const half8*)(Ap + 16 * D_ + kn);
            #pragma unroll
            for (int ni = 0; ni < 4; ni++) {
                nb[ni][0] = *(const floatx4*)(Bp[ni] + kn);
                nb[ni][1] = *(const floatx4*)(Bp[ni] + kn + 4);
            }
        }
        #pragma unroll
        for (int ni = 0; ni < 4; ni++) {
            half8 b = cvt8(bb[ni][0], bb[ni][1]);
            acc[0][ni] = __builtin_amdgcn_mfma_f32_16x16x32_f16(a0, b, acc[0][ni], 0, 0, 0);
            acc[1][ni] = __builtin_amdgcn_mfma_f32_16x16x32_f16(a1, b, acc[1][ni], 0, 0, 0);
        }
        a0 = na0; a1 = na1;
        #pragma unroll
        for (int ni = 0; ni < 4; ni++) { bb[ni][0] = nb[ni][0]; bb[ni][1] = nb[ni][1]; }
    }
    float bias[4];
    #pragma unroll
    for (int ni = 0; ni < 4; ni++)
        bias[ni] = b1[(size_t)e * H_ + ncol + ni * 16 + l16];
    #pragma unroll
    for (int mi = 0; mi < 2; mi++) {
        #pragma unroll
        for (int r = 0; r < 4; r++) {
            int rr = mi * 16 + quad * 4 + r;
            if (rr >= cnt) continue;
            size_t rowoff = (size_t)(row0 + rr) * H_;
            #pragma unroll
            for (int ni = 0; ni < 4; ni++) {
                float v = acc[mi][ni][r] + bias[ni];
                Y1[rowoff + ncol + ni * 16 + l16] = (half_t)gelu_f(v);
            }
        }
    }
}

// ---------------- GEMM2 (split-K=4): Y2p[kz] = Y1 @ W2[e]^T ----------------
// jobs: 256 m-slots x 8 n-tiles x 4 kz = 8192 waves; block = 4 kz of one (mslot,nc)
__global__ __launch_bounds__(256, 3) void gemm2_kernel(
        const half_t* __restrict__ Y1, const float* __restrict__ w2,
        const int* __restrict__ cnt_g, float* __restrict__ Y2p) {
    int wave = threadIdx.x >> 6, lane = threadIdx.x & 63;
    int quad = lane >> 4, l16 = lane & 15;
    int job = blockIdx.x * 4 + wave;
    int kz = job & 3, nc = (job >> 2) & 7, mslot = job >> 5;
    int ncol = nc * 64, kzb = kz * 512;
    int e = mslot >> 5, ti = mslot & 31;
    int valid = cnt_g[e] - ti * 32;
    if (valid <= 0) return;
    int cnt = valid < 32 ? valid : 32;
    int row0 = e * CAP + ti * 32;

    const half_t* Ap = Y1 + (size_t)(row0 + l16) * H_ + kzb + quad * 8;
    const float* Bp[4];
    #pragma unroll
    for (int ni = 0; ni < 4; ni++)
        Bp[ni] = w2 + ((size_t)e * D_ + ncol + ni * 16 + l16) * H_ + kzb + quad * 8;

    half8 a0 = *(const half8*)(Ap);
    half8 a1 = *(const half8*)(Ap + 16 * H_);
    floatx4 bb[4][2];
    #pragma unroll
    for (int ni = 0; ni < 4; ni++) {
        bb[ni][0] = *(const floatx4*)(Bp[ni]);
        bb[ni][1] = *(const floatx4*)(Bp[ni] + 4);
    }
    floatx4 acc[2][4] = {};
    for (int ks = 0; ks < 16; ks++) {
        int kn = (ks + 1) * 32;
        half8 na0, na1;
        floatx4 nb[4][2];
        if (ks < 15) {
            na0 = *(const half8*)(Ap + kn);
            na1 = *(const half8*)(Ap + 16 * H_ + kn);
            #pragma unroll
            for (int ni = 0; ni < 4; ni++) {
                nb[ni][0] = *(const floatx4*)(Bp[ni] + kn);
                nb[ni][1] = *(const floatx4*)(Bp[ni] + kn + 4);
            }
        }
        #pragma unroll
        for (int ni = 0; ni < 4; ni++) {
            half8 b = cvt8(bb[ni][0], bb[ni][1]);
            acc[0][ni] = __builtin_amdgcn_mfma_f32_16x16x32_f16(a0, b, acc[0][ni], 0, 0, 0);
            acc[1][ni] = __builtin_amdgcn_mfma_f32_16x16x32_f16(a1, b, acc[1][ni], 0, 0, 0);
        }
        a0 = na0; a1 = na1;
        #pragma unroll
        for (int ni = 0; ni < 4; ni++) { bb[ni][0] = nb[ni][0]; bb[ni][1] = nb[ni][1]; }
    }
    #pragma unroll
    for (int mi = 0; mi < 2; mi++) {
        #pragma unroll
        for (int r = 0; r < 4; r++) {
            int rr = mi * 16 + quad * 4 + r;
            if (rr >= cnt) continue;
            size_t rowoff = ((size_t)kz * (E_ * CAP) + row0 + rr) * D_;
            #pragma unroll
            for (int ni = 0; ni < 4; ni++)
                Y2p[rowoff + ncol + ni * 16 + l16] = acc[mi][ni][r];
        }
    }
}

// ---------------- combine + bias + LayerNorm, wave per token ----------------
__global__ __launch_bounds__(256) void final_kernel(
        const float* __restrict__ Y2p, const float* __restrict__ b2,
        const int* __restrict__ idx, const float* __restrict__ score,
        const int* __restrict__ pos_of_pair,
        const float* __restrict__ ln_w, const float* __restrict__ ln_b,
        float* __restrict__ out) {
    int n = blockIdx.x * 4 + (threadIdx.x >> 6);
    int lane = threadIdx.x & 63;
    int p0 = pos_of_pair[2 * n], p1 = pos_of_pair[2 * n + 1];
    int e0 = idx[2 * n], e1 = idx[2 * n + 1];
    float s0 = score[2 * n], s1 = score[2 * n + 1];

    const floatx4* b2r0 = (const floatx4*)(b2 + (size_t)e0 * D_);
    const floatx4* b2r1 = (const floatx4*)(b2 + (size_t)e1 * D_);
    floatx4 a_lo = b2r0[lane * 2], a_hi = b2r0[lane * 2 + 1];
    floatx4 c_lo = b2r1[lane * 2], c_hi = b2r1[lane * 2 + 1];
    #pragma unroll
    for (int kz = 0; kz < 4; kz++) {
        const floatx4* r0 = (const floatx4*)(Y2p + ((size_t)kz * (E_ * CAP) + p0) * D_);
        const floatx4* r1 = (const floatx4*)(Y2p + ((size_t)kz * (E_ * CAP) + p1) * D_);
        a_lo += r0[lane * 2]; a_hi += r0[lane * 2 + 1];
        c_lo += r1[lane * 2]; c_hi += r1[lane * 2 + 1];
    }
    floatx4 y_lo = s0 * a_lo + s1 * c_lo;
    floatx4 y_hi = s0 * a_hi + s1 * c_hi;

    float s = 0.0f, q = 0.0f;
    #pragma unroll
    for (int j = 0; j < 4; j++) {
        s += y_lo[j] + y_hi[j];
        q += y_lo[j] * y_lo[j] + y_hi[j] * y_hi[j];
    }
    #pragma unroll
    for (int m = 1; m < 64; m <<= 1) {
        s += __shfl_xor(s, m);
        q += __shfl_xor(q, m);
    }
    float mean = s * (1.0f / 512.0f);
    float var = q * (1.0f / 512.0f) - mean * mean;
    float inv = 1.0f / sqrtf(var + 1e-5f);

    const floatx4* wv = (const floatx4*)ln_w;
    const floatx4* bv = (const floatx4*)ln_b;
    floatx4 o_lo = (y_lo - mean) * inv * wv[lane * 2]     + bv[lane * 2];
    floatx4 o_hi = (y_hi - mean) * inv * wv[lane * 2 + 1] + bv[lane * 2 + 1];
    floatx4* op = (floatx4*)(out + (size_t)n * D_);
    op[lane * 2] = o_lo;
    op[lane * 2 + 1] = o_hi;
}

extern "C" void kernel_launch(void* const* d_in, const int* in_sizes, int n_in,
                              void* d_out, int out_size, void* d_ws, size_t ws_size,
                              hipStream_t stream) {
    const float* inp    = (const float*)d_in[0];
    const float* gate_w = (const float*)d_in[1];
    const float* gate_b = (const float*)d_in[2];
    const float* w1     = (const float*)d_in[3];
    const float* b1     = (const float*)d_in[4];
    const float* w2     = (const float*)d_in[5];
    const float* b2     = (const float*)d_in[6];
    const float* ln_w   = (const float*)d_in[7];
    const float* ln_b   = (const float*)d_in[8];
    float* out = (float*)d_out;

    char* ws = (char*)d_ws;
    size_t o = 0;
    auto carve = [&](size_t bytes) -> char* {
        char* p = ws + o;
        o += (bytes + 255) & ~(size_t)255;
        return p;
    };
    half_t* Xg  = (half_t*)carve(sizeof(half_t) * (size_t)E_ * CAP * D_);         // 8 MB
    half_t* Y1  = (half_t*)carve(sizeof(half_t) * (size_t)E_ * CAP * H_);         // 32 MB
    float*  Y2p = (float*)carve(sizeof(float) * 4 * (size_t)E_ * CAP * D_);       // 64 MB
    float*  score = (float*)carve(sizeof(float) * NP);
    int* idx         = (int*)carve(sizeof(int) * NP);
    int* pos_of_pair = (int*)carve(sizeof(int) * NP);
    int* cnt_g       = (int*)carve(sizeof(int) * E_);

    hipMemsetAsync(cnt_g, 0, sizeof(int) * E_, stream);
    gate_scatter_kernel<<<NTOK / 4, 256, 0, stream>>>(inp, gate_w, gate_b,
                                                      score, idx, pos_of_pair, cnt_g, Xg);
    gemm1_kernel<<<2048, 256, 0, stream>>>(Xg, w1, b1, cnt_g, Y1);
    gemm2_kernel<<<2048, 256, 0, stream>>>(Y1, w2, cnt_g, Y2p);
    final_kernel<<<NTOK / 4, 256, 0, stream>>>(Y2p, b2, idx, score, pos_of_pair, ln_w, ln_b, out);
}

// Round 7
// 223.407 us; speedup vs baseline: 1.4371x; 1.4371x over previous
//
#include <hip/hip_runtime.h>
#include <cstdint>
#include <cstddef>

typedef _Float16 half_t;
typedef _Float16 half8 __attribute__((ext_vector_type(8)));
typedef float floatx4 __attribute__((ext_vector_type(4)));

#define E_ 8
#define D_ 512
#define H_ 2048
#define NTOK 1024
#define NP 2048
#define CAP 1024           // per-expert row capacity
#define NC1 16             // gemm1: H/128 col-chunks
#define KS1 16             // gemm1: D/32 k-steps
#define NC2 4              // gemm2: D/128 col-chunks
#define KS2 64             // gemm2: H/32 k-steps
#define NCVT 1024          // cvt blocks in fused cvt+gate kernel

__device__ __forceinline__ float gelu_f(float x) {
    return 0.5f * x * (1.0f + erff(x * 0.7071067811865476f));
}

// async global->LDS, 16B/lane; LDS dest = wave-uniform base + lane*16
__device__ __forceinline__ void gload_lds16(const half_t* g, half_t* l) {
    __builtin_amdgcn_global_load_lds(
        (__attribute__((address_space(1))) void*)(g),
        (__attribute__((address_space(3))) void*)(l),
        16, 0, 0);
}

// ---------------- fused: weight tiling (fp32 -> fragment-contiguous f16) + gate+scatter ----------------
// blocks [0,NCVT): tiling. blocks [NCVT, NCVT+256): gate, 4 tokens each.
// W1t layout: [e][nc(16)][ks(16)][nt(8)][lane(64)*8 halfs]  (1 KB per fragment-block)
// W2t layout: [e][nc(4)][ks(64)][nt(8)][lane*8]
__global__ __launch_bounds__(256) void cvt_gate_kernel(
        const float* __restrict__ w1, const float* __restrict__ w2,
        half_t* __restrict__ W1t, half_t* __restrict__ W2t,
        const float* __restrict__ inp, const float* __restrict__ gate_w,
        const float* __restrict__ gate_b,
        float* __restrict__ score, int* __restrict__ idx,
        int* __restrict__ pos_of_pair, int* __restrict__ cnt_g,
        half_t* __restrict__ Xg) {
    const int blk = blockIdx.x, tid = threadIdx.x;
    const int wave = tid >> 6, lane = tid & 63;
    const int quad = lane >> 4, l16 = lane & 15;
    if (blk < NCVT) {
        int job = blk * 4 + wave;          // 0..4095
        const float* src; half_t* dst; int rowbase, kk, rstride;
        if (job < 2048) {                  // w1: e*256 + nc*16 + ks
            int e = job >> 8, nc = (job >> 4) & 15, ks = job & 15;
            src = w1 + (size_t)e * H_ * D_;
            dst = W1t + ((size_t)(e * NC1 + nc) * KS1 + ks) * 4096;
            rowbase = nc * 128;
            kk = ks * 32 + quad * 8;
            rstride = D_;
        } else {                           // w2: e*256 + nc*64 + ks
            int j = job - 2048;
            int e = j >> 8, nc = (j >> 6) & 3, ks = j & 63;
            src = w2 + (size_t)e * D_ * H_;
            dst = W2t + ((size_t)(e * NC2 + nc) * KS2 + ks) * 4096;
            rowbase = nc * 128;
            kk = ks * 32 + quad * 8;
            rstride = H_;
        }
        #pragma unroll
        for (int nt = 0; nt < 8; nt++) {
            int row = rowbase + nt * 16 + l16;
            const floatx4* s = (const floatx4*)(src + (size_t)row * rstride + kk);
            floatx4 f0 = s[0], f1 = s[1];
            half8 h = { (half_t)f0[0], (half_t)f0[1], (half_t)f0[2], (half_t)f0[3],
                        (half_t)f1[0], (half_t)f1[1], (half_t)f1[2], (half_t)f1[3] };
            *(half8*)(dst + nt * 512 + lane * 8) = h;
        }
        return;
    }
    // ---- gate ----
    int n = (blk - NCVT) * 4 + wave;
    const floatx4* xr = (const floatx4*)(inp + (size_t)n * D_);
    floatx4 x0 = xr[lane * 2], x1 = xr[lane * 2 + 1];
    float l[E_];
    #pragma unroll
    for (int e = 0; e < E_; e++) {
        const floatx4* gr = (const floatx4*)(gate_w + (size_t)e * D_);
        floatx4 g0 = gr[lane * 2], g1 = gr[lane * 2 + 1];
        float p = x0[0]*g0[0] + x0[1]*g0[1] + x0[2]*g0[2] + x0[3]*g0[3]
                + x1[0]*g1[0] + x1[1]*g1[1] + x1[2]*g1[2] + x1[3]*g1[3];
        #pragma unroll
        for (int m = 1; m < 64; m <<= 1) p += __shfl_xor(p, m);
        l[e] = p + gate_b[e];
    }
    int e0 = 0; float v0 = l[0];
    #pragma unroll
    for (int e = 1; e < E_; e++) if (l[e] > v0) { v0 = l[e]; e0 = e; }
    int e1 = -1; float v1 = -3.4e38f;
    #pragma unroll
    for (int e = 0; e < E_; e++) if (e != e0 && l[e] > v1) { v1 = l[e]; e1 = e; }
    int p0 = 0, p1 = 0;
    if (lane == 0) {
        float s1 = expf(v1 - v0);
        float den = 1.0f + s1;
        score[2 * n]     = 1.0f / den;
        score[2 * n + 1] = s1 / den;
        idx[2 * n]     = e0;
        idx[2 * n + 1] = e1;
        p0 = e0 * CAP + atomicAdd(&cnt_g[e0], 1);
        p1 = e1 * CAP + atomicAdd(&cnt_g[e1], 1);
        pos_of_pair[2 * n]     = p0;
        pos_of_pair[2 * n + 1] = p1;
    }
    p0 = __shfl(p0, 0);
    p1 = __shfl(p1, 0);
    half8 h = { (half_t)x0[0], (half_t)x0[1], (half_t)x0[2], (half_t)x0[3],
                (half_t)x1[0], (half_t)x1[1], (half_t)x1[2], (half_t)x1[3] };
    *(half8*)(Xg + (size_t)p0 * D_ + lane * 8) = h;
    *(half8*)(Xg + (size_t)p1 * D_ + lane * 8) = h;
}

// ======== GEMM: 32x128 block, A in LDS (one barrier), B streamed coalesced from tiled f16 ========
// LDS A layout: panel ks (32 k) : [row(32) x 64 B]; 16 panels (gemm1) = 32 KB.
// Stage: call c: dest d = c*4096 + tid*16 (bytes); j=d>>11, row=(d>>6)&31, kq=(d>>4)&3;
//        src = Abase + row*strideA + j*32 + kq*8  (halfs)

// ---------------- GEMM1: Y1[slab] = gelu(Xg @ W1[e]^T + b1[e]) ----------------
__global__ __launch_bounds__(256, 4) void gemm1_kernel(
        const half_t* __restrict__ Xg, const half_t* __restrict__ W1t,
        const float* __restrict__ b1, const int* __restrict__ cnt_g,
        half_t* __restrict__ Y1) {
    __shared__ half_t As[32 * 512];    // 32 KB
    int slot = blockIdx.x;             // e*32 + ti
    int e = slot >> 5, ti = slot & 31;
    int valid = cnt_g[e] - ti * 32;
    if (valid <= 0) return;
    int cnt = valid < 32 ? valid : 32;
    int row0 = e * CAP + ti * 32;
    int nc = blockIdx.y;
    int tid = threadIdx.x;
    int wave = tid >> 6, lane = tid & 63, quad = lane >> 4, l16 = lane & 15;

    const half_t* Abase = Xg + (size_t)row0 * D_;
    #pragma unroll
    for (int c = 0; c < 8; c++) {
        int d = c * 4096 + tid * 16;
        int j = d >> 11, row = (d >> 6) & 31, kq = (d >> 4) & 3;
        gload_lds16(Abase + (size_t)row * D_ + j * 32 + kq * 8, As + (d >> 1));
    }
    __syncthreads();

    const half_t* Bp = W1t + ((size_t)(e * NC1 + nc) * KS1) * 4096 + (2 * wave) * 512 + lane * 8;
    floatx4 acc[2][2] = {};
    #pragma unroll
    for (int ks = 0; ks < KS1; ks++) {
        half8 b0 = *(const half8*)(Bp + ks * 4096);
        half8 b1v = *(const half8*)(Bp + ks * 4096 + 512);
        half8 a0 = *(const half8*)(As + ks * 1024 + l16 * 32 + quad * 8);
        half8 a1 = *(const half8*)(As + ks * 1024 + (16 + l16) * 32 + quad * 8);
        acc[0][0] = __builtin_amdgcn_mfma_f32_16x16x32_f16(a0, b0, acc[0][0], 0, 0, 0);
        acc[0][1] = __builtin_amdgcn_mfma_f32_16x16x32_f16(a0, b1v, acc[0][1], 0, 0, 0);
        acc[1][0] = __builtin_amdgcn_mfma_f32_16x16x32_f16(a1, b0, acc[1][0], 0, 0, 0);
        acc[1][1] = __builtin_amdgcn_mfma_f32_16x16x32_f16(a1, b1v, acc[1][1], 0, 0, 0);
    }
    int n0 = nc * 128 + wave * 32;
    #pragma unroll
    for (int nt = 0; nt < 2; nt++) {
        int col = n0 + nt * 16 + l16;
        float bias = b1[(size_t)e * H_ + col];
        #pragma unroll
        for (int mi = 0; mi < 2; mi++) {
            #pragma unroll
            for (int r = 0; r < 4; r++) {
                int rr = mi * 16 + quad * 4 + r;
                if (rr >= cnt) continue;
                Y1[(size_t)(row0 + rr) * H_ + col] = (half_t)gelu_f(acc[mi][nt][r] + bias);
            }
        }
    }
}

// ---------------- GEMM2 (split-K=4): Y2p[kz] = Y1 @ W2[e]^T ----------------
__global__ __launch_bounds__(256, 4) void gemm2_kernel(
        const half_t* __restrict__ Y1, const half_t* __restrict__ W2t,
        const int* __restrict__ cnt_g, float* __restrict__ Y2p) {
    __shared__ half_t As[32 * 512];
    int slot = blockIdx.x;
    int e = slot >> 5, ti = slot & 31;
    int valid = cnt_g[e] - ti * 32;
    if (valid <= 0) return;
    int cnt = valid < 32 ? valid : 32;
    int row0 = e * CAP + ti * 32;
    int nc = blockIdx.y, kz = blockIdx.z;
    int kzb = kz * 512;
    int tid = threadIdx.x;
    int wave = tid >> 6, lane = tid & 63, quad = lane >> 4, l16 = lane & 15;

    const half_t* Abase = Y1 + (size_t)row0 * H_ + kzb;
    #pragma unroll
    for (int c = 0; c < 8; c++) {
        int d = c * 4096 + tid * 16;
        int j = d >> 11, row = (d >> 6) & 31, kq = (d >> 4) & 3;
        gload_lds16(Abase + (size_t)row * H_ + j * 32 + kq * 8, As + (d >> 1));
    }
    __syncthreads();

    const half_t* Bp = W2t + ((size_t)(e * NC2 + nc) * KS2 + kz * 16) * 4096 + (2 * wave) * 512 + lane * 8;
    floatx4 acc[2][2] = {};
    #pragma unroll
    for (int ks = 0; ks < 16; ks++) {
        half8 b0 = *(const half8*)(Bp + ks * 4096);
        half8 b1v = *(const half8*)(Bp + ks * 4096 + 512);
        half8 a0 = *(const half8*)(As + ks * 1024 + l16 * 32 + quad * 8);
        half8 a1 = *(const half8*)(As + ks * 1024 + (16 + l16) * 32 + quad * 8);
        acc[0][0] = __builtin_amdgcn_mfma_f32_16x16x32_f16(a0, b0, acc[0][0], 0, 0, 0);
        acc[0][1] = __builtin_amdgcn_mfma_f32_16x16x32_f16(a0, b1v, acc[0][1], 0, 0, 0);
        acc[1][0] = __builtin_amdgcn_mfma_f32_16x16x32_f16(a1, b0, acc[1][0], 0, 0, 0);
        acc[1][1] = __builtin_amdgcn_mfma_f32_16x16x32_f16(a1, b1v, acc[1][1], 0, 0, 0);
    }
    int n0 = nc * 128 + wave * 32;
    #pragma unroll
    for (int nt = 0; nt < 2; nt++) {
        int col = n0 + nt * 16 + l16;
        #pragma unroll
        for (int mi = 0; mi < 2; mi++) {
            #pragma unroll
            for (int r = 0; r < 4; r++) {
                int rr = mi * 16 + quad * 4 + r;
                if (rr >= cnt) continue;
                Y2p[((size_t)kz * (E_ * CAP) + row0 + rr) * D_ + col] = acc[mi][nt][r];
            }
        }
    }
}

// ---------------- combine + bias + LayerNorm, wave per token ----------------
__global__ __launch_bounds__(256) void final_kernel(
        const float* __restrict__ Y2p, const float* __restrict__ b2,
        const int* __restrict__ idx, const float* __restrict__ score,
        const int* __restrict__ pos_of_pair,
        const float* __restrict__ ln_w, const float* __restrict__ ln_b,
        float* __restrict__ out) {
    int n = blockIdx.x * 4 + (threadIdx.x >> 6);
    int lane = threadIdx.x & 63;
    int p0 = pos_of_pair[2 * n], p1 = pos_of_pair[2 * n + 1];
    int e0 = idx[2 * n], e1 = idx[2 * n + 1];
    float s0 = score[2 * n], s1 = score[2 * n + 1];

    const floatx4* b2r0 = (const floatx4*)(b2 + (size_t)e0 * D_);
    const floatx4* b2r1 = (const floatx4*)(b2 + (size_t)e1 * D_);
    floatx4 a_lo = b2r0[lane * 2], a_hi = b2r0[lane * 2 + 1];
    floatx4 c_lo = b2r1[lane * 2], c_hi = b2r1[lane * 2 + 1];
    #pragma unroll
    for (int kz = 0; kz < 4; kz++) {
        const floatx4* r0 = (const floatx4*)(Y2p + ((size_t)kz * (E_ * CAP) + p0) * D_);
        const floatx4* r1 = (const floatx4*)(Y2p + ((size_t)kz * (E_ * CAP) + p1) * D_);
        a_lo += r0[lane * 2]; a_hi += r0[lane * 2 + 1];
        c_lo += r1[lane * 2]; c_hi += r1[lane * 2 + 1];
    }
    floatx4 y_lo = s0 * a_lo + s1 * c_lo;
    floatx4 y_hi = s0 * a_hi + s1 * c_hi;

    float s = 0.0f, q = 0.0f;
    #pragma unroll
    for (int j = 0; j < 4; j++) {
        s += y_lo[j] + y_hi[j];
        q += y_lo[j] * y_lo[j] + y_hi[j] * y_hi[j];
    }
    #pragma unroll
    for (int m = 1; m < 64; m <<= 1) {
        s += __shfl_xor(s, m);
        q += __shfl_xor(q, m);
    }
    float mean = s * (1.0f / 512.0f);
    float var = q * (1.0f / 512.0f) - mean * mean;
    float inv = 1.0f / sqrtf(var + 1e-5f);

    const floatx4* wv = (const floatx4*)ln_w;
    const floatx4* bv = (const floatx4*)ln_b;
    floatx4 o_lo = (y_lo - mean) * inv * wv[lane * 2]     + bv[lane * 2];
    floatx4 o_hi = (y_hi - mean) * inv * wv[lane * 2 + 1] + bv[lane * 2 + 1];
    floatx4* op = (floatx4*)(out + (size_t)n * D_);
    op[lane * 2] = o_lo;
    op[lane * 2 + 1] = o_hi;
}

extern "C" void kernel_launch(void* const* d_in, const int* in_sizes, int n_in,
                              void* d_out, int out_size, void* d_ws, size_t ws_size,
                              hipStream_t stream) {
    const float* inp    = (const float*)d_in[0];
    const float* gate_w = (const float*)d_in[1];
    const float* gate_b = (const float*)d_in[2];
    const float* w1     = (const float*)d_in[3];
    const float* b1     = (const float*)d_in[4];
    const float* w2     = (const float*)d_in[5];
    const float* b2     = (const float*)d_in[6];
    const float* ln_w   = (const float*)d_in[7];
    const float* ln_b   = (const float*)d_in[8];
    float* out = (float*)d_out;

    char* ws = (char*)d_ws;
    size_t o = 0;
    auto carve = [&](size_t bytes) -> char* {
        char* p = ws + o;
        o += (bytes + 255) & ~(size_t)255;
        return p;
    };
    half_t* W1t = (half_t*)carve(sizeof(half_t) * (size_t)E_ * H_ * D_);          // 16 MB
    half_t* W2t = (half_t*)carve(sizeof(half_t) * (size_t)E_ * D_ * H_);          // 16 MB
    half_t* Xg  = (half_t*)carve(sizeof(half_t) * (size_t)E_ * CAP * D_);         // 8 MB
    half_t* Y1  = (half_t*)carve(sizeof(half_t) * (size_t)E_ * CAP * H_);         // 32 MB
    float*  Y2p = (float*)carve(sizeof(float) * 4 * (size_t)E_ * CAP * D_);       // 64 MB
    float*  score = (float*)carve(sizeof(float) * NP);
    int* idx         = (int*)carve(sizeof(int) * NP);
    int* pos_of_pair = (int*)carve(sizeof(int) * NP);
    int* cnt_g       = (int*)carve(sizeof(int) * E_);

    hipMemsetAsync(cnt_g, 0, sizeof(int) * E_, stream);
    cvt_gate_kernel<<<NCVT + NTOK / 4, 256, 0, stream>>>(
        w1, w2, W1t, W2t, inp, gate_w, gate_b,
        score, idx, pos_of_pair, cnt_g, Xg);
    gemm1_kernel<<<dim3(E_ * (CAP / 32), NC1), 256, 0, stream>>>(Xg, W1t, b1, cnt_g, Y1);
    gemm2_kernel<<<dim3(E_ * (CAP / 32), NC2, 4), 256, 0, stream>>>(Y1, W2t, cnt_g, Y2p);
    final_kernel<<<NTOK / 4, 256, 0, stream>>>(Y2p, b2, idx, score, pos_of_pair, ln_w, ln_b, out);
}